// Round 5
// baseline (506.849 us; speedup 1.0000x reference)
//
#include <hip/hip_runtime.h>
#include <math.h>

typedef _Float16 f16;
typedef _Float16 f16x4 __attribute__((ext_vector_type(4)));
typedef short short8 __attribute__((ext_vector_type(8)));
typedef float f32x4 __attribute__((ext_vector_type(4)));

#define NROWS (8 * 2048 * 16)   // B*S*G rows of D=64
#define BLOCK 512
#define WAVES 8
#define NITER 4                 // 16-row groups per wave
#define NT 20                   // 320/16 code tiles
#define GRID 512                // 512*8 waves * 4 iters * 16 rows = 262144
#define TAU 3e-4f               // rescue threshold ~60x logit err (~5e-6)

__device__ __forceinline__ short f2bf(float f) {
    unsigned u = __builtin_bit_cast(unsigned, f);
    return (short)((u + 0x7fffu + ((u >> 16) & 1u)) >> 16);
}
__device__ __forceinline__ float bf2f(short h) {
    return __builtin_bit_cast(float, ((unsigned)(unsigned short)h) << 16);
}

// NOTE: no min-waves arg in __launch_bounds__. LDS (124 KB) already limits
// us to 1 block/CU; adding ",2" caps VGPR at 128 and spills acc[20] to
// scratch (r4: 1.5 GB HBM spill traffic, 488 us). Default 256-VGPR cap: no spill.
__global__ __launch_bounds__(BLOCK) void vq_mfma(
    const float* __restrict__ inputs,   // [262144][64]
    const int* __restrict__ mask,       // [16384]
    const float* __restrict__ Wcb,      // [64][320]
    const float* __restrict__ bcb,      // [320]
    const float* __restrict__ codevec,  // [320][64]
    float* __restrict__ out_cv,         // [262144][64]
    float* __restrict__ out_cw)         // [262144] as float
{
    // W^T bf16 limbs, swizzled: row n(code), d in 8 slots of 8, slot' = slot^(n&7)
    __shared__ __align__(16) short Wh[320 * 64];
    __shared__ __align__(16) short Wl[320 * 64];
    // CV^T f16 for K=16 PV: elem = d*320 + (((k>>2)^(d&15))<<2) + (k&3)
    __shared__ __align__(16) f16 CVf[64 * 320];
    __shared__ __align__(16) float bs[320];

    const int tid = threadIdx.x;

    for (int e = tid; e < 64 * 320; e += BLOCK) {
        int d = e / 320, n = e - d * 320;
        float w = Wcb[e];
        short wh = f2bf(w);
        short wl = f2bf(w - bf2f(wh));
        int s = d >> 3;
        int idx = n * 64 + (((s ^ n) & 7) << 3) + (d & 7);
        Wh[idx] = wh;
        Wl[idx] = wl;
    }
    for (int e = tid; e < 320 * 64; e += BLOCK) {
        int k = e >> 6, d = e & 63;
        CVf[d * 320 + ((((k >> 2) ^ (d & 15)) << 2)) + (k & 3)] = (f16)codevec[e];
    }
    for (int e = tid; e < 320; e += BLOCK) bs[e] = bcb[e];
    __syncthreads();

    const int wid = tid >> 6;
    const int lane = tid & 63;
    const int l15 = lane & 15;          // C column = data row
    const int lg = lane >> 4;           // frag k-group 0..3
    const int l7 = l15 & 7;
    const int u = blockIdx.x * WAVES + wid;   // 0..4095

    #pragma unroll 1
    for (int it = 0; it < NITER; ++it) {
        const int row0 = u * (NITER * 16) + it * 16;
        const float* xrow = inputs + (size_t)(row0 + l15) * 64;

        // ---- x B-frags, 2 bf16 limbs (no subnormal hazard) ----
        short8 xh[2], xl[2];
        #pragma unroll
        for (int kc = 0; kc < 2; ++kc) {
            float4 a = *(const float4*)(xrow + kc * 32 + lg * 8);
            float4 b = *(const float4*)(xrow + kc * 32 + lg * 8 + 4);
            float xv[8] = {a.x, a.y, a.z, a.w, b.x, b.y, b.z, b.w};
            short8 h, l;
            #pragma unroll
            for (int e = 0; e < 8; ++e) {
                short hh = f2bf(xv[e]);
                h[e] = hh;
                l[e] = f2bf(xv[e] - bf2f(hh));
            }
            xh[kc] = h;
            xl[kc] = l;
        }

        // ---- logits: acc = bias + wh*xh + wh*xl + wl*xh ----
        f32x4 acc[NT];
        #pragma unroll
        for (int nt = 0; nt < NT; ++nt) {
            acc[nt] = *(const f32x4*)&bs[nt * 16 + lg * 4];   // bias as C-init
            #pragma unroll
            for (int kc = 0; kc < 2; ++kc) {
                int base = (nt * 16 + l15) * 64 + ((((kc * 4 + lg) ^ l7) & 7) << 3);
                short8 whf = *(const short8*)&Wh[base];
                short8 wlf = *(const short8*)&Wl[base];
                acc[nt] = __builtin_amdgcn_mfma_f32_16x16x32_bf16(whf, xl[kc], acc[nt], 0, 0, 0);
                acc[nt] = __builtin_amdgcn_mfma_f32_16x16x32_bf16(wlf, xh[kc], acc[nt], 0, 0, 0);
                acc[nt] = __builtin_amdgcn_mfma_f32_16x16x32_bf16(whf, xh[kc], acc[nt], 0, 0, 0);
            }
        }

        // ---- top-2 max / argmax (first-index tie-break) ----
        float m1 = -INFINITY, m2 = -INFINITY;
        int i1 = 0;
        #pragma unroll
        for (int nt = 0; nt < NT; ++nt) {
            #pragma unroll
            for (int r = 0; r < 4; ++r) {
                float v = acc[nt][r];
                m2 = fmaxf(m2, fminf(m1, v));
                if (v > m1) { m1 = v; i1 = nt * 16 + lg * 4 + r; }
            }
        }
        #pragma unroll
        for (int dx = 16; dx <= 32; dx <<= 1) {
            float mo = __shfl_xor(m1, dx, 64);
            int io = __shfl_xor(i1, dx, 64);
            float m2o = __shfl_xor(m2, dx, 64);
            m2 = fmaxf(fmaxf(m2, m2o), fminf(m1, mo));
            if (mo > m1 || (mo == m1 && io < i1)) { m1 = mo; i1 = io; }
        }

        // ---- exact-argmax rescue for near-ties (rare: ~3% of wave-iters) ----
        const int mk = mask[u * NITER + it];   // wave-uniform
        int cw = i1;
        const bool flag = mk && (m1 - m2 < TAU);
        if (__any(flag)) {
            const float thr = m1 - TAU;
            int c0 = -1, c1 = -1, c2 = -1;
            if (flag) {
                #pragma unroll
                for (int nt = 0; nt < NT; ++nt) {
                    #pragma unroll
                    for (int r = 0; r < 4; ++r) {
                        if (acc[nt][r] >= thr) {
                            int c = nt * 16 + lg * 4 + r;
                            if (c0 < 0) c0 = c;
                            else if (c1 < 0) c1 = c;
                            else if (c2 < 0) c2 = c;
                        }
                    }
                }
            }
            float bv = -INFINITY;
            int bi = 0x7fffffff;
            #pragma unroll 1
            for (int t = 0; t < 3; ++t) {
                int c = (t == 0) ? c0 : ((t == 1) ? c1 : c2);
                if (__any(c >= 0)) {
                    if (c >= 0) {
                        float sacc = bs[c];
                        #pragma unroll 8
                        for (int d = 0; d < 64; ++d)
                            sacc = fmaf(xrow[d], Wcb[d * 320 + c], sacc);
                        if (sacc > bv || (sacc == bv && c < bi)) { bv = sacc; bi = c; }
                    }
                }
            }
            #pragma unroll
            for (int dx = 16; dx <= 32; dx <<= 1) {
                float vo = __shfl_xor(bv, dx, 64);
                int io = __shfl_xor(bi, dx, 64);
                if (vo > bv || (vo == bv && io < bi)) { bv = vo; bi = io; }
            }
            if (flag) cw = bi;
        }

        // ---- exp + row sum (probs overwrite acc) ----
        float sum = 0.f;
        #pragma unroll
        for (int nt = 0; nt < NT; ++nt) {
            #pragma unroll
            for (int r = 0; r < 4; ++r) {
                float p = __expf(acc[nt][r] - m1);
                acc[nt][r] = p;
                sum += p;
            }
        }
        sum += __shfl_xor(sum, 16, 64);
        sum += __shfl_xor(sum, 32, 64);

        // ---- PV via K=16 MFMA: B-frag == acc[nt][0..3] directly, no transpose ----
        f32x4 cv[4];
        #pragma unroll
        for (int dt = 0; dt < 4; ++dt) cv[dt] = (f32x4){0.f, 0.f, 0.f, 0.f};
        #pragma unroll
        for (int nt = 0; nt < NT; ++nt) {
            f16x4 pf;
            #pragma unroll
            for (int r = 0; r < 4; ++r) pf[r] = (f16)acc[nt][r];
            const f16* ap = &CVf[l15 * 320 + (((nt * 4 + lg) ^ l15) << 2)];
            #pragma unroll
            for (int dt = 0; dt < 4; ++dt) {
                f16x4 cf = *(const f16x4*)(ap + dt * 5120);
                cv[dt] = __builtin_amdgcn_mfma_f32_16x16x16f16(cf, pf, cv[dt], 0, 0, 0);
            }
        }

        // ---- epilogue: mask, normalize, store ----
        const float inv = mk ? (1.0f / sum) : 0.0f;
        float* orow = out_cv + (size_t)(row0 + l15) * 64;
        #pragma unroll
        for (int dt = 0; dt < 4; ++dt) {
            f32x4 v;
            v[0] = cv[dt][0] * inv;
            v[1] = cv[dt][1] * inv;
            v[2] = cv[dt][2] * inv;
            v[3] = cv[dt][3] * inv;
            *(f32x4*)(orow + dt * 16 + lg * 4) = v;
        }
        if (lg == 0) out_cw[row0 + l15] = mk ? (float)cw : 0.0f;
    }
}

extern "C" void kernel_launch(void* const* d_in, const int* in_sizes, int n_in,
                              void* d_out, int out_size, void* d_ws, size_t ws_size,
                              hipStream_t stream) {
    const float* inputs  = (const float*)d_in[0];
    const int*   mask    = (const int*)d_in[1];
    const float* Wcb     = (const float*)d_in[2];
    const float* bcb     = (const float*)d_in[3];
    const float* codevec = (const float*)d_in[4];

    float* out_cv = (float*)d_out;
    float* out_cw = out_cv + (size_t)NROWS * 64;

    vq_mfma<<<GRID, BLOCK, 0, stream>>>(inputs, mask, Wcb, bcb, codevec, out_cv, out_cw);
}

// Round 6
// 497.809 us; speedup vs baseline: 1.0182x; 1.0182x over previous
//
#include <hip/hip_runtime.h>
#include <math.h>

typedef _Float16 f16;
typedef _Float16 f16x4 __attribute__((ext_vector_type(4)));
typedef short short8 __attribute__((ext_vector_type(8)));
typedef float f32x4 __attribute__((ext_vector_type(4)));

#define NROWS (8 * 2048 * 16)   // B*S*G rows of D=64
#define BLOCK 512
#define WAVES 8
#define NITER 4                 // 16-row groups per wave
#define NT 20                   // 320/16 code tiles
#define GRID 512                // 512*8 waves * 4 iters * 16 rows = 262144
#define TAU 3e-4f               // rescue threshold ~60x logit err (~5e-6)

__device__ __forceinline__ short f2bf(float f) {
    unsigned u = __builtin_bit_cast(unsigned, f);
    return (short)((u + 0x7fffu + ((u >> 16) & 1u)) >> 16);
}
__device__ __forceinline__ float bf2f(short h) {
    return __builtin_bit_cast(float, ((unsigned)(unsigned short)h) << 16);
}

// launch_bounds(512, 1): min-waves/EU = 1 relaxes the allocator's default
// 4-waves/EU register budget (which pinned VGPR=128 in r4/r5 and spilled
// acc[20] -> 1.4 GB scratch HBM traffic). Flat workgroup size 512 (8 waves,
// 2/SIMD) still clamps allocation to <=256 VGPR, which costs no occupancy:
// LDS (124 KB) already limits us to 1 block/CU.
__global__ __launch_bounds__(BLOCK, 1) void vq_mfma(
    const float* __restrict__ inputs,   // [262144][64]
    const int* __restrict__ mask,       // [16384]
    const float* __restrict__ Wcb,      // [64][320]
    const float* __restrict__ bcb,      // [320]
    const float* __restrict__ codevec,  // [320][64]
    float* __restrict__ out_cv,         // [262144][64]
    float* __restrict__ out_cw)         // [262144] as float
{
    // W^T bf16 limbs, swizzled: row n(code), d in 8 slots of 8, slot' = slot^(n&7)
    __shared__ __align__(16) short Wh[320 * 64];
    __shared__ __align__(16) short Wl[320 * 64];
    // CV^T f16 for K=16 PV: elem = d*320 + (((k>>2)^(d&15))<<2) + (k&3)
    __shared__ __align__(16) f16 CVf[64 * 320];
    __shared__ __align__(16) float bs[320];

    const int tid = threadIdx.x;

    for (int e = tid; e < 64 * 320; e += BLOCK) {
        int d = e / 320, n = e - d * 320;
        float w = Wcb[e];
        short wh = f2bf(w);
        short wl = f2bf(w - bf2f(wh));
        int s = d >> 3;
        int idx = n * 64 + (((s ^ n) & 7) << 3) + (d & 7);
        Wh[idx] = wh;
        Wl[idx] = wl;
    }
    for (int e = tid; e < 320 * 64; e += BLOCK) {
        int k = e >> 6, d = e & 63;
        CVf[d * 320 + ((((k >> 2) ^ (d & 15)) << 2)) + (k & 3)] = (f16)codevec[e];
    }
    for (int e = tid; e < 320; e += BLOCK) bs[e] = bcb[e];
    __syncthreads();

    const int wid = tid >> 6;
    const int lane = tid & 63;
    const int l15 = lane & 15;          // C column = data row
    const int lg = lane >> 4;           // frag k-group 0..3
    const int l7 = l15 & 7;
    const int u = blockIdx.x * WAVES + wid;   // 0..4095

    #pragma unroll 1
    for (int it = 0; it < NITER; ++it) {
        const int row0 = u * (NITER * 16) + it * 16;
        const float* xrow = inputs + (size_t)(row0 + l15) * 64;

        // ---- x B-frags, 2 bf16 limbs (no subnormal hazard) ----
        short8 xh[2], xl[2];
        #pragma unroll
        for (int kc = 0; kc < 2; ++kc) {
            float4 a = *(const float4*)(xrow + kc * 32 + lg * 8);
            float4 b = *(const float4*)(xrow + kc * 32 + lg * 8 + 4);
            float xv[8] = {a.x, a.y, a.z, a.w, b.x, b.y, b.z, b.w};
            short8 h, l;
            #pragma unroll
            for (int e = 0; e < 8; ++e) {
                short hh = f2bf(xv[e]);
                h[e] = hh;
                l[e] = f2bf(xv[e] - bf2f(hh));
            }
            xh[kc] = h;
            xl[kc] = l;
        }

        // ---- logits: acc = bias + wh*xh + wh*xl + wl*xh ----
        f32x4 acc[NT];
        #pragma unroll
        for (int nt = 0; nt < NT; ++nt) {
            acc[nt] = *(const f32x4*)&bs[nt * 16 + lg * 4];   // bias as C-init
            #pragma unroll
            for (int kc = 0; kc < 2; ++kc) {
                int base = (nt * 16 + l15) * 64 + ((((kc * 4 + lg) ^ l7) & 7) << 3);
                short8 whf = *(const short8*)&Wh[base];
                short8 wlf = *(const short8*)&Wl[base];
                acc[nt] = __builtin_amdgcn_mfma_f32_16x16x32_bf16(whf, xl[kc], acc[nt], 0, 0, 0);
                acc[nt] = __builtin_amdgcn_mfma_f32_16x16x32_bf16(wlf, xh[kc], acc[nt], 0, 0, 0);
                acc[nt] = __builtin_amdgcn_mfma_f32_16x16x32_bf16(whf, xh[kc], acc[nt], 0, 0, 0);
            }
        }

        // ---- top-2 max / argmax (first-index tie-break) ----
        float m1 = -INFINITY, m2 = -INFINITY;
        int i1 = 0;
        #pragma unroll
        for (int nt = 0; nt < NT; ++nt) {
            #pragma unroll
            for (int r = 0; r < 4; ++r) {
                float v = acc[nt][r];
                m2 = fmaxf(m2, fminf(m1, v));
                if (v > m1) { m1 = v; i1 = nt * 16 + lg * 4 + r; }
            }
        }
        #pragma unroll
        for (int dx = 16; dx <= 32; dx <<= 1) {
            float mo = __shfl_xor(m1, dx, 64);
            int io = __shfl_xor(i1, dx, 64);
            float m2o = __shfl_xor(m2, dx, 64);
            m2 = fmaxf(fmaxf(m2, m2o), fminf(m1, mo));
            if (mo > m1 || (mo == m1 && io < i1)) { m1 = mo; i1 = io; }
        }

        // ---- exact-argmax rescue for near-ties (rare: ~3% of wave-iters) ----
        const int mk = mask[u * NITER + it];   // wave-uniform
        int cw = i1;
        const bool flag = mk && (m1 - m2 < TAU);
        if (__any(flag)) {
            const float thr = m1 - TAU;
            int c0 = -1, c1 = -1, c2 = -1;
            if (flag) {
                #pragma unroll
                for (int nt = 0; nt < NT; ++nt) {
                    #pragma unroll
                    for (int r = 0; r < 4; ++r) {
                        if (acc[nt][r] >= thr) {
                            int c = nt * 16 + lg * 4 + r;
                            if (c0 < 0) c0 = c;
                            else if (c1 < 0) c1 = c;
                            else if (c2 < 0) c2 = c;
                        }
                    }
                }
            }
            float bv = -INFINITY;
            int bi = 0x7fffffff;
            #pragma unroll 1
            for (int t = 0; t < 3; ++t) {
                int c = (t == 0) ? c0 : ((t == 1) ? c1 : c2);
                if (__any(c >= 0)) {
                    if (c >= 0) {
                        float sacc = bs[c];
                        #pragma unroll 8
                        for (int d = 0; d < 64; ++d)
                            sacc = fmaf(xrow[d], Wcb[d * 320 + c], sacc);
                        if (sacc > bv || (sacc == bv && c < bi)) { bv = sacc; bi = c; }
                    }
                }
            }
            #pragma unroll
            for (int dx = 16; dx <= 32; dx <<= 1) {
                float vo = __shfl_xor(bv, dx, 64);
                int io = __shfl_xor(bi, dx, 64);
                if (vo > bv || (vo == bv && io < bi)) { bv = vo; bi = io; }
            }
            if (flag) cw = bi;
        }

        // ---- exp + row sum (probs overwrite acc) ----
        float sum = 0.f;
        #pragma unroll
        for (int nt = 0; nt < NT; ++nt) {
            #pragma unroll
            for (int r = 0; r < 4; ++r) {
                float p = __expf(acc[nt][r] - m1);
                acc[nt][r] = p;
                sum += p;
            }
        }
        sum += __shfl_xor(sum, 16, 64);
        sum += __shfl_xor(sum, 32, 64);

        // ---- PV via K=16 MFMA: B-frag == acc[nt][0..3] directly, no transpose ----
        f32x4 cv[4];
        #pragma unroll
        for (int dt = 0; dt < 4; ++dt) cv[dt] = (f32x4){0.f, 0.f, 0.f, 0.f};
        #pragma unroll
        for (int nt = 0; nt < NT; ++nt) {
            f16x4 pf;
            #pragma unroll
            for (int r = 0; r < 4; ++r) pf[r] = (f16)acc[nt][r];
            const f16* ap = &CVf[l15 * 320 + (((nt * 4 + lg) ^ l15) << 2)];
            #pragma unroll
            for (int dt = 0; dt < 4; ++dt) {
                f16x4 cf = *(const f16x4*)(ap + dt * 5120);
                cv[dt] = __builtin_amdgcn_mfma_f32_16x16x16f16(cf, pf, cv[dt], 0, 0, 0);
            }
        }

        // ---- epilogue: mask, normalize, store ----
        const float inv = mk ? (1.0f / sum) : 0.0f;
        float* orow = out_cv + (size_t)(row0 + l15) * 64;
        #pragma unroll
        for (int dt = 0; dt < 4; ++dt) {
            f32x4 v;
            v[0] = cv[dt][0] * inv;
            v[1] = cv[dt][1] * inv;
            v[2] = cv[dt][2] * inv;
            v[3] = cv[dt][3] * inv;
            *(f32x4*)(orow + dt * 16 + lg * 4) = v;
        }
        if (lg == 0) out_cw[row0 + l15] = mk ? (float)cw : 0.0f;
    }
}

extern "C" void kernel_launch(void* const* d_in, const int* in_sizes, int n_in,
                              void* d_out, int out_size, void* d_ws, size_t ws_size,
                              hipStream_t stream) {
    const float* inputs  = (const float*)d_in[0];
    const int*   mask    = (const int*)d_in[1];
    const float* Wcb     = (const float*)d_in[2];
    const float* bcb     = (const float*)d_in[3];
    const float* codevec = (const float*)d_in[4];

    float* out_cv = (float*)d_out;
    float* out_cw = out_cv + (size_t)NROWS * 64;

    vq_mfma<<<GRID, BLOCK, 0, stream>>>(inputs, mask, Wcb, bcb, codevec, out_cv, out_cw);
}

// Round 7
// 102.850 us; speedup vs baseline: 4.9281x; 4.8402x over previous
//
#include <hip/hip_runtime.h>
#include <math.h>

typedef _Float16 f16;
typedef _Float16 f16x4 __attribute__((ext_vector_type(4)));
typedef short short8 __attribute__((ext_vector_type(8)));
typedef float f32x4 __attribute__((ext_vector_type(4)));

#define NROWS (8 * 2048 * 16)   // B*S*G rows of D=64
#define BLOCK 512
#define WAVES 8
#define NITER 4                 // 16-row groups per wave
#define GRID 512                // 512*8 waves * 4 iters * 16 rows = 262144
#define TAU 3e-4f               // rescue threshold ~60x logit err (~5e-6)

__device__ __forceinline__ short f2bf(float f) {
    unsigned u = __builtin_bit_cast(unsigned, f);
    return (short)((u + 0x7fffu + ((u >> 16) & 1u)) >> 16);
}
__device__ __forceinline__ float bf2f(short h) {
    return __builtin_bit_cast(float, ((unsigned)(unsigned short)h) << 16);
}

// One half (160 codes = 10 tiles) of the logit/softmax/PV pipeline.
// Keeping only 10 acc tiles live (40 VGPRs) fits the allocator's 128-VGPR
// budget for 512-thread blocks (r4-r6: 20 live tiles -> scratch spill,
// 1.4 GB of HBM spill traffic). Online-softmax merge between halves.
template <int HB, bool FIRST>
__device__ __forceinline__ void half_pass(
    const short* __restrict__ Wh, const short* __restrict__ Wl,
    const f16* __restrict__ CVf, const float* __restrict__ bs,
    const short8 (&xh)[2], const short8 (&xl)[2],
    int l15, int lg, int l7,
    f32x4 (&cv)[4], float& m_run, float& sum_run,
    float& m1o, float& m2o, int& i1o, int& c0, int& c1, int& c2)
{
    // ---- logits for this half: acc = bias + wh*xh + wh*xl + wl*xh ----
    f32x4 acc[10];
    #pragma unroll
    for (int nt = 0; nt < 10; ++nt) {
        const int ntg = HB / 16 + nt;
        acc[nt] = *(const f32x4*)&bs[ntg * 16 + lg * 4];   // bias as C-init
        #pragma unroll
        for (int kc = 0; kc < 2; ++kc) {
            int base = (ntg * 16 + l15) * 64 + ((((kc * 4 + lg) ^ l7) & 7) << 3);
            short8 whf = *(const short8*)&Wh[base];
            short8 wlf = *(const short8*)&Wl[base];
            acc[nt] = __builtin_amdgcn_mfma_f32_16x16x32_bf16(whf, xl[kc], acc[nt], 0, 0, 0);
            acc[nt] = __builtin_amdgcn_mfma_f32_16x16x32_bf16(wlf, xh[kc], acc[nt], 0, 0, 0);
            acc[nt] = __builtin_amdgcn_mfma_f32_16x16x32_bf16(whf, xh[kc], acc[nt], 0, 0, 0);
        }
    }

    // ---- per-half top-2 / argmax (first-index tie-break) ----
    float m1 = -INFINITY, m2 = -INFINITY;
    int i1 = HB;
    #pragma unroll
    for (int nt = 0; nt < 10; ++nt) {
        #pragma unroll
        for (int r = 0; r < 4; ++r) {
            float v = acc[nt][r];
            m2 = fmaxf(m2, fminf(m1, v));
            if (v > m1) { m1 = v; i1 = HB + nt * 16 + lg * 4 + r; }
        }
    }
    #pragma unroll
    for (int dx = 16; dx <= 32; dx <<= 1) {
        float mo = __shfl_xor(m1, dx, 64);
        int io = __shfl_xor(i1, dx, 64);
        float m2x = __shfl_xor(m2, dx, 64);
        m2 = fmaxf(fmaxf(m2, m2x), fminf(m1, mo));
        if (mo > m1 || (mo == m1 && io < i1)) { m1 = mo; i1 = io; }
    }

    // ---- candidate collection, gated on per-half near-tie.
    // Correctness: the true argmax c* has approx logit > m1_global - TAU, so
    // either c* == i1 of its half (always a candidate) or its half has a
    // near-tie and the scan collects it.
    c0 = -1; c1 = -1; c2 = -1;
    if (m1 - m2 < TAU) {
        const float thr = m1 - TAU;
        #pragma unroll
        for (int nt = 0; nt < 10; ++nt) {
            #pragma unroll
            for (int r = 0; r < 4; ++r) {
                if (acc[nt][r] >= thr) {
                    int c = HB + nt * 16 + lg * 4 + r;
                    if (c0 < 0) c0 = c;
                    else if (c1 < 0) c1 = c;
                    else if (c2 < 0) c2 = c;
                }
            }
        }
    }

    // ---- online-softmax merge: rescale running cv/sum, exp this half ----
    float mnew = m1;
    if (!FIRST) {
        mnew = fmaxf(m_run, m1);
        float sc = __expf(m_run - mnew);
        sum_run *= sc;
        #pragma unroll
        for (int dt = 0; dt < 4; ++dt) {
            cv[dt][0] *= sc; cv[dt][1] *= sc; cv[dt][2] *= sc; cv[dt][3] *= sc;
        }
    }
    float s = 0.f;
    #pragma unroll
    for (int nt = 0; nt < 10; ++nt) {
        #pragma unroll
        for (int r = 0; r < 4; ++r) {
            float p = __expf(acc[nt][r] - mnew);
            acc[nt][r] = p;
            s += p;
        }
    }
    sum_run = FIRST ? s : (sum_run + s);
    m_run = mnew;

    // ---- PV via K=16 MFMA: B-frag == acc[nt][0..3] directly, no transpose ----
    #pragma unroll
    for (int nt = 0; nt < 10; ++nt) {
        const int ntg = HB / 16 + nt;
        f16x4 pf;
        #pragma unroll
        for (int r = 0; r < 4; ++r) pf[r] = (f16)acc[nt][r];
        const f16* ap = &CVf[l15 * 320 + (((ntg * 4 + lg) ^ l15) << 2)];
        #pragma unroll
        for (int dt = 0; dt < 4; ++dt) {
            f16x4 cf = *(const f16x4*)(ap + dt * 5120);
            cv[dt] = __builtin_amdgcn_mfma_f32_16x16x16f16(cf, pf, cv[dt], 0, 0, 0);
        }
    }
    m1o = m1; m2o = m2; i1o = i1;
}

__global__ __launch_bounds__(BLOCK) void vq_mfma(
    const float* __restrict__ inputs,   // [262144][64]
    const int* __restrict__ mask,       // [16384]
    const float* __restrict__ Wcb,      // [64][320]
    const float* __restrict__ bcb,      // [320]
    const float* __restrict__ codevec,  // [320][64]
    float* __restrict__ out_cv,         // [262144][64]
    float* __restrict__ out_cw)         // [262144] as float
{
    // W^T bf16 limbs, swizzled: row n(code), d in 8 slots of 8, slot' = slot^(n&7)
    __shared__ __align__(16) short Wh[320 * 64];
    __shared__ __align__(16) short Wl[320 * 64];
    // CV^T f16 for K=16 PV: elem = d*320 + (((k>>2)^(d&15))<<2) + (k&3)
    __shared__ __align__(16) f16 CVf[64 * 320];
    __shared__ __align__(16) float bs[320];

    const int tid = threadIdx.x;

    for (int e = tid; e < 64 * 320; e += BLOCK) {
        int d = e / 320, n = e - d * 320;
        float w = Wcb[e];
        short wh = f2bf(w);
        short wl = f2bf(w - bf2f(wh));
        int s = d >> 3;
        int idx = n * 64 + (((s ^ n) & 7) << 3) + (d & 7);
        Wh[idx] = wh;
        Wl[idx] = wl;
    }
    for (int e = tid; e < 320 * 64; e += BLOCK) {
        int k = e >> 6, d = e & 63;
        CVf[d * 320 + ((((k >> 2) ^ (d & 15)) << 2)) + (k & 3)] = (f16)codevec[e];
    }
    for (int e = tid; e < 320; e += BLOCK) bs[e] = bcb[e];
    __syncthreads();

    const int wid = tid >> 6;
    const int lane = tid & 63;
    const int l15 = lane & 15;          // C column = data row
    const int lg = lane >> 4;           // frag k-group 0..3
    const int l7 = l15 & 7;
    const int u = blockIdx.x * WAVES + wid;   // 0..4095

    #pragma unroll 1
    for (int it = 0; it < NITER; ++it) {
        const int row0 = u * (NITER * 16) + it * 16;
        const float* xrow = inputs + (size_t)(row0 + l15) * 64;

        // ---- x B-frags, 2 bf16 limbs (no subnormal hazard) ----
        short8 xh[2], xl[2];
        #pragma unroll
        for (int kc = 0; kc < 2; ++kc) {
            float4 a = *(const float4*)(xrow + kc * 32 + lg * 8);
            float4 b = *(const float4*)(xrow + kc * 32 + lg * 8 + 4);
            float xv[8] = {a.x, a.y, a.z, a.w, b.x, b.y, b.z, b.w};
            short8 h, l;
            #pragma unroll
            for (int e = 0; e < 8; ++e) {
                short hh = f2bf(xv[e]);
                h[e] = hh;
                l[e] = f2bf(xv[e] - bf2f(hh));
            }
            xh[kc] = h;
            xl[kc] = l;
        }

        f32x4 cv[4];
        #pragma unroll
        for (int dt = 0; dt < 4; ++dt) cv[dt] = (f32x4){0.f, 0.f, 0.f, 0.f};
        float m_run = 0.f, sum_run = 0.f;
        float m1A, m2A, m1B, m2B;
        int i1A, i1B, cA0, cA1, cA2, cB0, cB1, cB2;

        half_pass<0, true>(Wh, Wl, CVf, bs, xh, xl, l15, lg, l7,
                           cv, m_run, sum_run, m1A, m2A, i1A, cA0, cA1, cA2);
        half_pass<160, false>(Wh, Wl, CVf, bs, xh, xl, l15, lg, l7,
                              cv, m_run, sum_run, m1B, m2B, i1B, cB0, cB1, cB2);

        // ---- merge halves: global top-2 / argmax ----
        float m1 = m1A;
        int i1 = i1A;
        float m2 = fmaxf(fmaxf(m2A, m2B), fminf(m1A, m1B));
        if (m1B > m1) { m1 = m1B; i1 = i1B; }   // tie -> half A (smaller index)

        float sum = sum_run;
        sum += __shfl_xor(sum, 16, 64);
        sum += __shfl_xor(sum, 32, 64);

        // ---- exact-argmax rescue for near-ties ----
        const int mk = mask[u * NITER + it];   // wave-uniform
        int cw = i1;
        const bool flag = mk && (m1 - m2 < TAU);
        if (__any(flag)) {
            float bv = -INFINITY;
            int bi = 0x7fffffff;
            #pragma unroll 1
            for (int t = 0; t < 8; ++t) {
                int c = (t == 0) ? i1A : (t == 1) ? i1B :
                        (t == 2) ? cA0 : (t == 3) ? cA1 : (t == 4) ? cA2 :
                        (t == 5) ? cB0 : (t == 6) ? cB1 : cB2;
                if (!flag) c = -1;
                if (__any(c >= 0)) {
                    if (c >= 0) {
                        float sacc = bs[c];
                        #pragma unroll 8
                        for (int d = 0; d < 64; ++d)
                            sacc = fmaf(xrow[d], Wcb[d * 320 + c], sacc);
                        if (sacc > bv || (sacc == bv && c < bi)) { bv = sacc; bi = c; }
                    }
                }
            }
            #pragma unroll
            for (int dx = 16; dx <= 32; dx <<= 1) {
                float vo = __shfl_xor(bv, dx, 64);
                int io = __shfl_xor(bi, dx, 64);
                if (vo > bv || (vo == bv && io < bi)) { bv = vo; bi = io; }
            }
            if (flag) cw = bi;
        }

        // ---- epilogue: mask, normalize, store ----
        const float inv = mk ? (1.0f / sum) : 0.0f;
        float* orow = out_cv + (size_t)(row0 + l15) * 64;
        #pragma unroll
        for (int dt = 0; dt < 4; ++dt) {
            f32x4 v;
            v[0] = cv[dt][0] * inv;
            v[1] = cv[dt][1] * inv;
            v[2] = cv[dt][2] * inv;
            v[3] = cv[dt][3] * inv;
            *(f32x4*)(orow + dt * 16 + lg * 4) = v;
        }
        if (lg == 0) out_cw[row0 + l15] = mk ? (float)cw : 0.0f;
    }
}

extern "C" void kernel_launch(void* const* d_in, const int* in_sizes, int n_in,
                              void* d_out, int out_size, void* d_ws, size_t ws_size,
                              hipStream_t stream) {
    const float* inputs  = (const float*)d_in[0];
    const int*   mask    = (const int*)d_in[1];
    const float* Wcb     = (const float*)d_in[2];
    const float* bcb     = (const float*)d_in[3];
    const float* codevec = (const float*)d_in[4];

    float* out_cv = (float*)d_out;
    float* out_cw = out_cv + (size_t)NROWS * 64;

    vq_mfma<<<GRID, BLOCK, 0, stream>>>(inputs, mask, Wcb, bcb, codevec, out_cv, out_cw);
}